// Round 1
// baseline (3155.075 us; speedup 1.0000x reference)
//
#include <hip/hip_runtime.h>
#include <stdint.h>

typedef unsigned short u16;
typedef float f32x4 __attribute__((ext_vector_type(4)));
typedef __bf16 bf16x8 __attribute__((ext_vector_type(8)));
typedef unsigned short u16x8 __attribute__((ext_vector_type(8)));
typedef unsigned short u16x4 __attribute__((ext_vector_type(4)));

#define SEQ 128
#define BATCH 64
#define EMBD 512
#define HID 1024
#define VOCAB 32000
#define KCAT 1536               // EMBD + HID (fused [x;h] K)
#define SLOT (BATCH * KCAT)     // 98304 elems per timestep slot
#define NGATE 4096

// ---------- helpers ----------

__device__ __forceinline__ void gload_lds16(const void* g, void* l) {
  // async global->LDS, 16B per lane; LDS dest must be wave-uniform base + lane*16
  __builtin_amdgcn_global_load_lds(
      reinterpret_cast<__attribute__((address_space(1))) void*>(
          reinterpret_cast<uintptr_t>(g)),
      reinterpret_cast<__attribute__((address_space(3))) void*>(
          reinterpret_cast<uintptr_t>(l)),
      16, 0, 0);
}

__device__ __forceinline__ u16 f32_bf16(float f) {
  uint32_t u = __builtin_bit_cast(uint32_t, f);
  u += 0x7fffu + ((u >> 16) & 1u);
  return (u16)(u >> 16);
}

// ---------- weight prep ----------

// lin_W (32000,1024) fp32 -> bf16, same [n][k] layout (already B^T form)
__global__ __launch_bounds__(256) void k_conv_linW(const float* __restrict__ src,
                                                   u16* __restrict__ dst) {
  int i = blockIdx.x * 256 + threadIdx.x;  // float4 index; 8192000 total
  float4 v = reinterpret_cast<const float4*>(src)[i];
  u16x4 o;
  o.x = f32_bf16(v.x); o.y = f32_bf16(v.y); o.z = f32_bf16(v.z); o.w = f32_bf16(v.w);
  reinterpret_cast<u16x4*>(dst)[i] = o;
}

// fp32 src (R, C) -> bf16 dst[c*ldd + koff + r]  (transpose + convert)
__global__ __launch_bounds__(256) void k_transpose_conv(const float* __restrict__ src,
                                                        u16* __restrict__ dst,
                                                        int R, int C, int ldd, int koff) {
  __shared__ float tile[32][33];
  int tx = threadIdx.x;   // 0..31
  int ty = threadIdx.y;   // 0..7
  int r0 = blockIdx.y * 32;
  int c0 = blockIdx.x * 32;
#pragma unroll
  for (int i = 0; i < 4; ++i)
    tile[ty + i * 8][tx] = src[(size_t)(r0 + ty + i * 8) * C + c0 + tx];
  __syncthreads();
#pragma unroll
  for (int i = 0; i < 4; ++i) {
    int cc = ty + i * 8;
    dst[(size_t)(c0 + cc) * ldd + koff + r0 + tx] = f32_bf16(tile[tx][cc]);
  }
}

// embedding gather -> xcat slot-t x-part (row m = t*64+b)
__global__ __launch_bounds__(256) void k_embed(const int* __restrict__ inp,
                                               const float* __restrict__ emb,
                                               u16* __restrict__ xcat) {
  int m = blockIdx.x * 4 + (threadIdx.x >> 6);
  int l = threadIdx.x & 63;
  int id = inp[m];
  const float4* s = reinterpret_cast<const float4*>(emb + (size_t)id * EMBD + l * 8);
  float4 v0 = s[0], v1 = s[1];
  u16x8 o;
  o[0] = f32_bf16(v0.x); o[1] = f32_bf16(v0.y); o[2] = f32_bf16(v0.z); o[3] = f32_bf16(v0.w);
  o[4] = f32_bf16(v1.x); o[5] = f32_bf16(v1.y); o[6] = f32_bf16(v1.z); o[7] = f32_bf16(v1.w);
  *reinterpret_cast<u16x8*>(xcat + (size_t)m * KCAT + l * 8) = o;
}

// h0 -> xcat slot0 h-part (bf16); c0 -> c_ws; h0 -> h32
__global__ __launch_bounds__(256) void k_init_state(const float* __restrict__ h0,
                                                    const float* __restrict__ c0,
                                                    u16* __restrict__ xcat,
                                                    float* __restrict__ c_ws,
                                                    float* __restrict__ h32) {
  int i = blockIdx.x * 256 + threadIdx.x;  // 65536
  int b = i >> 10, k = i & 1023;
  c_ws[i] = c0[i];
  h32[i] = h0[i];
  xcat[(size_t)b * KCAT + EMBD + k] = f32_bf16(h0[i]);
}

// ---------- one LSTM timestep ----------
// 256 blocks x 256 threads. Block bid owns hid cols [bid*4, bid*4+4) i.e. 16
// gate columns n = g*1024 + bid*4 + r (n_local = g*4+r). gates = [x;h] @ WcatT.
__global__ __launch_bounds__(256) void k_lstm_step(u16* __restrict__ xcat,
                                                   const u16* __restrict__ WcatT,
                                                   const float* __restrict__ b_lstm,
                                                   float* __restrict__ c_ws,
                                                   float* __restrict__ h32,
                                                   int t) {
  const int BSTR = 1544;               // 1536 + 8 pad: bank-conflict-free b128 reads
  __shared__ u16 Bs[16 * 1544];        // 48.25 KB W-slice
  __shared__ float gsm[64][17];        // gate staging (D-layout -> per-thread)
  int tid = threadIdx.x;
  int l = tid & 63;
  int w = tid >> 6;
  int bid = blockIdx.x;

  // stage W-slice (register staging; padded LDS rows forbid global_load_lds)
  for (int i = 0; i < 12; ++i) {
    int c = i * 256 + tid;             // 0..3071, 192 16B-chunks per row
    int nl = c / 192;
    int kc = (c - nl * 192) * 8;
    int grow = ((nl >> 2) << 10) + (bid << 2) + (nl & 3);
    u16x8 v = *reinterpret_cast<const u16x8*>(WcatT + (size_t)grow * KCAT + kc);
    *reinterpret_cast<u16x8*>(&Bs[nl * BSTR + kc]) = v;
  }
  __syncthreads();

  // MFMA: wave w computes batch rows [w*16, w*16+16) x 16 gate cols, K=1536
  const u16* Ab = xcat + (size_t)t * SLOT + (size_t)(w * 16 + (l & 15)) * KCAT + ((l >> 4) * 8);
  const u16* Bb = &Bs[(l & 15) * BSTR + ((l >> 4) * 8)];
  f32x4 acc0 = {0.f, 0.f, 0.f, 0.f};
  f32x4 acc1 = {0.f, 0.f, 0.f, 0.f};
#pragma unroll 4
  for (int ki = 0; ki < 48; ki += 2) {
    bf16x8 a0 = *reinterpret_cast<const bf16x8*>(Ab + ki * 32);
    bf16x8 b0 = *reinterpret_cast<const bf16x8*>(Bb + ki * 32);
    bf16x8 a1 = *reinterpret_cast<const bf16x8*>(Ab + ki * 32 + 32);
    bf16x8 b1 = *reinterpret_cast<const bf16x8*>(Bb + ki * 32 + 32);
    acc0 = __builtin_amdgcn_mfma_f32_16x16x32_bf16(a0, b0, acc0, 0, 0, 0);
    acc1 = __builtin_amdgcn_mfma_f32_16x16x32_bf16(a1, b1, acc1, 0, 0, 0);
  }
  int rb = w * 16 + (l >> 4) * 4;
  int lc = l & 15;
#pragma unroll
  for (int r = 0; r < 4; ++r) gsm[rb + r][lc] = acc0[r] + acc1[r];
  __syncthreads();

  // elementwise: thread -> (batch b, local hid col jl)
  int b = tid >> 2, jl = tid & 3;
  int j = (bid << 2) + jl;
  float gi = gsm[b][jl]      + b_lstm[j];
  float gf = gsm[b][4 + jl]  + b_lstm[HID + j];
  float gg = gsm[b][8 + jl]  + b_lstm[2 * HID + j];
  float go = gsm[b][12 + jl] + b_lstm[3 * HID + j];
  float iv = 1.f / (1.f + __expf(-gi));
  float fv = 1.f / (1.f + __expf(-gf));
  float gv = tanhf(gg);
  float ov = 1.f / (1.f + __expf(-go));
  int ci = b * HID + j;
  float cn = fv * c_ws[ci] + iv * gv;
  c_ws[ci] = cn;
  float hv = ov * tanhf(cn);
  h32[ci] = hv;
  xcat[(size_t)(t + 1) * SLOT + (size_t)b * KCAT + EMBD + j] = f32_bf16(hv);
}

// ---------- big GEMM: C[m][n] = sum_k A[m][k]*B[n][k] + bias[n] ----------
// m97 structure: 128x128 tile, BK=64, 4 waves (2x2 of 64x64), global_load_lds.
__global__ __launch_bounds__(256) void k_gemm_bt_bias(const u16* __restrict__ A, int lda,
                                                      const u16* __restrict__ B, int ldb,
                                                      float* __restrict__ C, int ldc,
                                                      const float* __restrict__ bias,
                                                      int K) {
  __shared__ u16 As[128 * 64];
  __shared__ u16 Bsh[128 * 64];
  int tid = threadIdx.x;
  int l = tid & 63;
  int w = tid >> 6;
  int m0 = blockIdx.y * 128;
  int n0 = blockIdx.x * 128;
  int wm = (w >> 1) * 64;
  int wn = (w & 1) * 64;

  const f32x4 vz = {0.f, 0.f, 0.f, 0.f};
  f32x4 acc[4][4];
#pragma unroll
  for (int mi = 0; mi < 4; ++mi)
#pragma unroll
    for (int ni = 0; ni < 4; ++ni) acc[mi][ni] = vz;

  for (int k0 = 0; k0 < K; k0 += 64) {
#pragma unroll
    for (int i = 0; i < 4; ++i) {
      int c = i * 256 + tid;
      int row = c >> 3;
      int kc = (c & 7) * 8;
      gload_lds16(A + (size_t)(m0 + row) * lda + k0 + kc, &As[c * 8]);
      gload_lds16(B + (size_t)(n0 + row) * ldb + k0 + kc, &Bsh[c * 8]);
    }
    __syncthreads();
#pragma unroll
    for (int kk = 0; kk < 64; kk += 32) {
      bf16x8 af[4], bfr[4];
#pragma unroll
      for (int mi = 0; mi < 4; ++mi)
        af[mi] = *reinterpret_cast<const bf16x8*>(
            &As[(wm + mi * 16 + (l & 15)) * 64 + kk + ((l >> 4) * 8)]);
#pragma unroll
      for (int ni = 0; ni < 4; ++ni)
        bfr[ni] = *reinterpret_cast<const bf16x8*>(
            &Bsh[(wn + ni * 16 + (l & 15)) * 64 + kk + ((l >> 4) * 8)]);
#pragma unroll
      for (int mi = 0; mi < 4; ++mi)
#pragma unroll
        for (int ni = 0; ni < 4; ++ni)
          acc[mi][ni] = __builtin_amdgcn_mfma_f32_16x16x32_bf16(af[mi], bfr[ni],
                                                                acc[mi][ni], 0, 0, 0);
    }
    __syncthreads();
  }

  int lr = (l >> 4) * 4;
  int lc = l & 15;
#pragma unroll
  for (int ni = 0; ni < 4; ++ni) {
    int col = n0 + wn + ni * 16 + lc;
    float bv = bias[col];
#pragma unroll
    for (int mi = 0; mi < 4; ++mi) {
#pragma unroll
      for (int r = 0; r < 4; ++r) {
        int row = m0 + wm + mi * 16 + lr + r;
        C[(size_t)row * ldc + col] = acc[mi][ni][r] + bv;
      }
    }
  }
}

// ---------- tail: h_t, c_t (fp32 state) -> d_out ----------
__global__ __launch_bounds__(256) void k_tail(const float* __restrict__ h32,
                                              const float* __restrict__ c_ws,
                                              float* __restrict__ out) {
  int i = blockIdx.x * 256 + threadIdx.x;  // 131072
  if (i < 65536) out[i] = h32[i];
  else out[i] = c_ws[i - 65536];
}

extern "C" void kernel_launch(void* const* d_in, const int* in_sizes, int n_in,
                              void* d_out, int out_size, void* d_ws, size_t ws_size,
                              hipStream_t stream) {
  (void)in_sizes; (void)n_in; (void)out_size; (void)ws_size;
  const int*   inp    = (const int*)d_in[0];
  const float* emb    = (const float*)d_in[1];
  const float* W_ih   = (const float*)d_in[2];
  const float* W_hh   = (const float*)d_in[3];
  const float* b_lstm = (const float*)d_in[4];
  const float* lin_W  = (const float*)d_in[5];
  const float* lin_b  = (const float*)d_in[6];
  const float* h0     = (const float*)d_in[7];
  const float* c0     = (const float*)d_in[8];
  float* out = (float*)d_out;

  // workspace layout (~104 MB)
  u16* xcat   = (u16*)d_ws;                        // (129, 64, 1536) bf16: [x_t ; h_{t-1}]
  u16* WcatT  = xcat + (size_t)129 * SLOT;         // (4096, 1536) bf16: [W_ih;W_hh]^T
  u16* linWb  = WcatT + (size_t)NGATE * KCAT;      // (32000, 1024) bf16
  float* c_ws = (float*)(linWb + (size_t)VOCAB * HID);  // (64,1024) fp32 cell state
  float* h32  = c_ws + BATCH * HID;                // (64,1024) fp32 last h

  k_conv_linW<<<VOCAB * HID / 4 / 256, 256, 0, stream>>>(lin_W, linWb);
  k_transpose_conv<<<dim3(NGATE / 32, EMBD / 32), dim3(32, 8), 0, stream>>>(
      W_ih, WcatT, EMBD, NGATE, KCAT, 0);
  k_transpose_conv<<<dim3(NGATE / 32, HID / 32), dim3(32, 8), 0, stream>>>(
      W_hh, WcatT, HID, NGATE, KCAT, EMBD);
  k_embed<<<SEQ * BATCH / 4, 256, 0, stream>>>(inp, emb, xcat);
  k_init_state<<<BATCH * HID / 256, 256, 0, stream>>>(h0, c0, xcat, c_ws, h32);

  for (int t = 0; t < SEQ; ++t)
    k_lstm_step<<<256, 256, 0, stream>>>(xcat, WcatT, b_lstm, c_ws, h32, t);

  // logits: A = h-parts of slots 1..128 (row m = t*64+b), lda=KCAT
  k_gemm_bt_bias<<<dim3(VOCAB / 128, SEQ * BATCH / 128), 256, 0, stream>>>(
      xcat + SLOT + EMBD, KCAT, linWb, HID, out, VOCAB, lin_b, HID);

  k_tail<<<2 * BATCH * HID / 256, 256, 0, stream>>>(
      h32, c_ws, out + (size_t)SEQ * BATCH * VOCAB);
}